// Round 5
// baseline (134.936 us; speedup 1.0000x reference)
//
#include <hip/hip_runtime.h>
#include <hip/hip_bf16.h>

#define DI __device__ __forceinline__
#define MFMA __builtin_amdgcn_mfma_f32_16x16x32_bf16

typedef __attribute__((ext_vector_type(8))) short bf16x8;   // 8 bf16 = 4 VGPRs (MFMA A/B frag)
typedef __attribute__((ext_vector_type(4))) short s16x4;    // 4 bf16 = 8 B (ds_write_b64)
typedef __attribute__((ext_vector_type(4))) float f32x4;    // MFMA C/D frag

constexpr int HW = 4096;
constexpr int SAS = 72;            // ic-stride in shorts (36 dwords -> 2-way banks, free)
constexpr int FR  = 66 * SAS;      // 4752 shorts per frame (66 cols x 72)
constexpr int N2R = 64 * SAS;      // n2 scratch row
constexpr int L_N2 = 8 * FR;       // n2 region after the 8 frames
constexpr int LDS_SHORTS = L_N2 + 4 * N2R;   // 56448 shorts = 112,896 B

// ---- workspace layout (bytes): weights only (~240 KB) ----
constexpr size_t OFF_WB3  = 0;                       // bf16 [3][9][64oc][64ic]
constexpr size_t OFF_WB1  = OFF_WB3 + 221184;        // bf16 [2][64oc][64ic]
constexpr size_t OFF_BIAS = OFF_WB1 + 16384;         // f32 [5][64]
constexpr size_t OFF_CC   = OFF_BIAS + 1280;         // int[2]

DI int argmax8(const float* __restrict__ a) {
    int best = 0; float bv = a[0];
#pragma unroll
    for (int i = 1; i < 8; ++i) { float v = a[i]; if (v > bv) { bv = v; best = i; } }
    return best;
}

DI short f2bf(float v) {
    __hip_bfloat16 h = __float2bfloat16(v);
    return __builtin_bit_cast(short, h);
}

// ---------------------------------------------------------------------------
// prep: c1,c2; weights -> bf16 frag order with BN scale + channel masks
// folded; per-edge bias (out-masked). Tiny kernel (~3 us).
// ---------------------------------------------------------------------------
__global__ __launch_bounds__(256) void prep_kernel(
    const float* __restrict__ w3, const float* __restrict__ w1,
    const float* __restrict__ bn, const float* __restrict__ a1,
    const float* __restrict__ a2, char* __restrict__ ws) {
    short* __restrict__ wb3  = (short*)(ws + OFF_WB3);
    short* __restrict__ wb1  = (short*)(ws + OFF_WB1);
    float* __restrict__ bias = (float*)(ws + OFF_BIAS);
    int*   __restrict__ cc   = (int*)(ws + OFF_CC);
    const int c1 = 8 * (argmax8(a1) + 1);
    const int c2 = 8 * (argmax8(a2) + 1);

    const int idx = blockIdx.x * 256 + threadIdx.x;
    if (idx < 110592) {                       // wb3 flat = ((e*9+kp)*64+oc)*64+ic
        const int e = idx / 36864, rem = idx % 36864;
        const int kp = rem >> 12, oc = (rem >> 6) & 63, ic = idx & 63;
        const int bnrow = (e == 0) ? 0 : (e == 1) ? 1 : 3;
        const float g = bn[(bnrow * 4 + 0) * 64 + oc];
        const float v = bn[(bnrow * 4 + 3) * 64 + oc];
        const float s = g * rsqrtf(v + 1e-5f);
        const float wv = w3[((e * 64 + oc) * 64 + ic) * 9 + kp];
        wb3[idx] = (oc < c2 && ic < c1) ? f2bf(wv * s) : (short)0;
    } else if (idx < 118784) {                // wb1 flat = (e*64+oc)*64+ic
        const int j = idx - 110592;
        const int e = j >> 12, oc = (j >> 6) & 63, ic = j & 63;
        const int bnrow = (e == 0) ? 2 : 4;
        const float g = bn[(bnrow * 4 + 0) * 64 + oc];
        const float v = bn[(bnrow * 4 + 3) * 64 + oc];
        const float s = g * rsqrtf(v + 1e-5f);
        wb1[j] = (oc < c2 && ic < c1) ? f2bf(w1[(e * 64 + oc) * 64 + ic] * s) : (short)0;
    } else if (idx < 119104) {                // bias
        const int j = idx - 118784;
        const int e = j >> 6, oc = j & 63;
        const float g = bn[(e * 4 + 0) * 64 + oc];
        const float b = bn[(e * 4 + 1) * 64 + oc];
        const float m = bn[(e * 4 + 2) * 64 + oc];
        const float v = bn[(e * 4 + 3) * 64 + oc];
        bias[j] = (oc < c2) ? (b - m * g * rsqrtf(v + 1e-5f)) : 0.f;
    } else if (idx == 119104) {
        cc[0] = c1; cc[1] = c2;
    }
}

// ---------------------------------------------------------------------------
// HALF-ROW conv helpers: each covers 32 px (mt in {2h, 2h+1}), 32-reg acc.
// All fully unrolled; all register indices compile-time; channel culls
// wave-uniform.
// ---------------------------------------------------------------------------
// dual 3x3 conv (e0+e1 of the SAME row): shared A-frags, two weight sets.
DI void conv3_dual_sw_half(const short* __restrict__ sA, int f0,
                           const short* __restrict__ W0v, const short* __restrict__ W1v,
                           int c1, int c2, int h, int lm, int q,
                           f32x4 (&a0)[2][4], f32x4 (&a1)[2][4]) {
#pragma unroll
    for (int ky = 0; ky < 3; ++ky)
#pragma unroll
        for (int kx = 0; kx < 3; ++kx) {
            const short* __restrict__ W0 = W0v + (ky * 3 + kx) * 4096;
            const short* __restrict__ W1 = W1v + (ky * 3 + kx) * 4096;
#pragma unroll
            for (int kc = 0; kc < 2; ++kc)
                if (kc == 0 || c1 > 32) {
                    bf16x8 af[2], b0[4], b1[4];
#pragma unroll
                    for (int nt = 0; nt < 4; ++nt)
                        if (nt * 16 < c2) {
                            b0[nt] = *(const bf16x8*)(W0 + (nt * 16 + lm) * 64 + kc * 32 + q * 8);
                            b1[nt] = *(const bf16x8*)(W1 + (nt * 16 + lm) * 64 + kc * 32 + q * 8);
                        }
#pragma unroll
                    for (int m = 0; m < 2; ++m)
                        af[m] = *(const bf16x8*)(&sA[((f0 + ky) * 66 + (2 * h + m) * 16 + lm + kx) * SAS + kc * 32 + q * 8]);
#pragma unroll
                    for (int nt = 0; nt < 4; ++nt)
                        if (nt * 16 < c2)
#pragma unroll
                            for (int m = 0; m < 2; ++m) {
                                a0[m][nt] = MFMA(b0[nt], af[m], a0[m][nt], 0, 0, 0);
                                a1[m][nt] = MFMA(b1[nt], af[m], a1[m][nt], 0, 0, 0);
                            }
                }
        }
}

// single 3x3 conv, swapped operands (halo e0 rows)
DI void conv3_sw_half(const short* __restrict__ sA, int f0,
                      const short* __restrict__ Wv, int c1, int c2,
                      int h, int lm, int q, f32x4 (&acc)[2][4]) {
#pragma unroll
    for (int ky = 0; ky < 3; ++ky)
#pragma unroll
        for (int kx = 0; kx < 3; ++kx) {
            const short* __restrict__ W = Wv + (ky * 3 + kx) * 4096;
#pragma unroll
            for (int kc = 0; kc < 2; ++kc)
                if (kc == 0 || c1 > 32) {
                    bf16x8 af[2], bfr[4];
#pragma unroll
                    for (int nt = 0; nt < 4; ++nt)
                        if (nt * 16 < c2)
                            bfr[nt] = *(const bf16x8*)(W + (nt * 16 + lm) * 64 + kc * 32 + q * 8);
#pragma unroll
                    for (int m = 0; m < 2; ++m)
                        af[m] = *(const bf16x8*)(&sA[((f0 + ky) * 66 + (2 * h + m) * 16 + lm + kx) * SAS + kc * 32 + q * 8]);
#pragma unroll
                    for (int nt = 0; nt < 4; ++nt)
                        if (nt * 16 < c2)
#pragma unroll
                            for (int m = 0; m < 2; ++m)
                                acc[m][nt] = MFMA(bfr[nt], af[m], acc[m][nt], 0, 0, 0);
                }
        }
}

// single 3x3 conv, NORMAL operands (e2; lane: oc=nt*16+lm, px=mtg*16+q*4+r)
DI void conv3_nm_half(const short* __restrict__ sA, int f0,
                      const short* __restrict__ Wv, int c1, int c2,
                      int h, int lm, int q, f32x4 (&acc)[2][4]) {
#pragma unroll
    for (int ky = 0; ky < 3; ++ky)
#pragma unroll
        for (int kx = 0; kx < 3; ++kx) {
            const short* __restrict__ W = Wv + (ky * 3 + kx) * 4096;
#pragma unroll
            for (int kc = 0; kc < 2; ++kc)
                if (kc == 0 || c1 > 32) {
                    bf16x8 af[2], bfr[4];
#pragma unroll
                    for (int nt = 0; nt < 4; ++nt)
                        if (nt * 16 < c2)
                            bfr[nt] = *(const bf16x8*)(W + (nt * 16 + lm) * 64 + kc * 32 + q * 8);
#pragma unroll
                    for (int m = 0; m < 2; ++m)
                        af[m] = *(const bf16x8*)(&sA[((f0 + ky) * 66 + (2 * h + m) * 16 + lm + kx) * SAS + kc * 32 + q * 8]);
#pragma unroll
                    for (int nt = 0; nt < 4; ++nt)
                        if (nt * 16 < c2)
#pragma unroll
                            for (int m = 0; m < 2; ++m)
                                acc[m][nt] = MFMA(af[m], bfr[nt], acc[m][nt], 0, 0, 0);
                }
        }
}

// 1x1 conv, swapped, accumulate (input = n1 slot row, col halo +1)
DI void conv1_sw_half(const short* __restrict__ sRow, const short* __restrict__ W1,
                      int c1, int c2, int h, int lm, int q, f32x4 (&acc)[2][4]) {
#pragma unroll
    for (int kc = 0; kc < 2; ++kc)
        if (kc == 0 || c1 > 32) {
            bf16x8 af[2], bfr[4];
#pragma unroll
            for (int m = 0; m < 2; ++m)
                af[m] = *(const bf16x8*)(&sRow[((2 * h + m) * 16 + lm + 1) * SAS + kc * 32 + q * 8]);
#pragma unroll
            for (int nt = 0; nt < 4; ++nt)
                if (nt * 16 < c2)
                    bfr[nt] = *(const bf16x8*)(W1 + (nt * 16 + lm) * 64 + kc * 32 + q * 8);
#pragma unroll
            for (int nt = 0; nt < 4; ++nt)
                if (nt * 16 < c2)
#pragma unroll
                    for (int m = 0; m < 2; ++m)
                        acc[m][nt] = MFMA(bfr[nt], af[m], acc[m][nt], 0, 0, 0);
        }
}

// 1x1 conv, normal, accumulate (input = [px][ic] n2 scratch, no halo)
DI void conv1_nm_half(const short* __restrict__ sRow, const short* __restrict__ W1,
                      int c1, int c2, int h, int lm, int q, f32x4 (&acc)[2][4]) {
#pragma unroll
    for (int kc = 0; kc < 2; ++kc)
        if (kc == 0 || c1 > 32) {
            bf16x8 af[2], bfr[4];
#pragma unroll
            for (int m = 0; m < 2; ++m)
                af[m] = *(const bf16x8*)(&sRow[((2 * h + m) * 16 + lm) * SAS + kc * 32 + q * 8]);
#pragma unroll
            for (int nt = 0; nt < 4; ++nt)
                if (nt * 16 < c2)
                    bfr[nt] = *(const bf16x8*)(W1 + (nt * 16 + lm) * 64 + kc * 32 + q * 8);
#pragma unroll
            for (int nt = 0; nt < 4; ++nt)
                if (nt * 16 < c2)
#pragma unroll
                    for (int m = 0; m < 2; ++m)
                        acc[m][nt] = MFMA(af[m], bfr[nt], acc[m][nt], 0, 0, 0);
        }
}

// relu+bias epi from a SWAPPED half-acc into a [px][SAS] row (b64 writes).
DI void epi_sw_half(short* __restrict__ dst, int colOff, const float* __restrict__ b0,
                    const float* __restrict__ b1, bool live, int h, int lm, int q,
                    const f32x4 (&acc)[2][4]) {
#pragma unroll
    for (int nt = 0; nt < 4; ++nt) {
        f32x4 bv = *(const f32x4*)(b0 + nt * 16 + q * 4);
        if (b1) {
            const f32x4 bvb = *(const f32x4*)(b1 + nt * 16 + q * 4);
#pragma unroll
            for (int r = 0; r < 4; ++r) bv[r] += bvb[r];
        }
#pragma unroll
        for (int m = 0; m < 2; ++m) {
            s16x4 pk = (s16x4)0;
            if (live) {
#pragma unroll
                for (int r = 0; r < 4; ++r)
                    pk[r] = f2bf(fmaxf(acc[m][nt][r] + bv[r], 0.f));
            }
            *(s16x4*)(&dst[((2 * h + m) * 16 + lm + colOff) * SAS + nt * 16 + q * 4]) = pk;
        }
    }
}

// ---------------------------------------------------------------------------
// Fused cell kernel, half-row job pool: 768 threads (12 waves, 3/SIMD),
// 4 out rows per block, 112.9 KB dynamic LDS, THREE barriers.
// P1 (after B1): waves 0-7 = (row r=w>>1, half h=w&1): e0 row r + e1 row r
//   with SHARED A-frags (2x 32-reg accs). Waves 8-11: halo e0 rows -1,4.
//   Exactly 720 MFMA per SIMD -> balanced.
// B2 -> n1 epi into frames -> B3 -> per-wave local stream (no more syncs):
//   conv1_e0-half (+= e1 acc) -> n2-half (own px half, own slot region) ->
//   conv1_e1-half -> e2-half conv3 accumulated into SAME final acc ->
//   + bias + skip -> coalesced f32x4 store. No p3 exchange, no B4.
// ---------------------------------------------------------------------------
__global__ __launch_bounds__(768, 3) void fused_cell_kernel(
    const float* __restrict__ x, const char* __restrict__ ws,
    float* __restrict__ outp) {
    extern __shared__ __align__(16) short sA[];
    const int t = threadIdx.x, w = t >> 6, l = t & 63, lm = l & 15, q = l >> 4;
    const int y0 = blockIdx.x * 4, n = blockIdx.y;
    const int* cc = (const int*)(ws + OFF_CC);
    const int c1 = __builtin_amdgcn_readfirstlane(cc[0]);
    const int c2 = __builtin_amdgcn_readfirstlane(cc[1]);
    const int SGm = (c1 > 32) ? 8 : 4;
    const float* __restrict__ bias = (const float*)(ws + OFF_BIAS);
    const short* __restrict__ WBe0 = (const short*)(ws + OFF_WB3);
    const short* __restrict__ WBe1 = WBe0 + 36864;
    const short* __restrict__ WBe2 = WBe0 + 2 * 36864;
    const short* __restrict__ W1e0 = (const short*)(ws + OFF_WB1);
    const short* __restrict__ W1e1 = W1e0 + 4096;

    // ---- P0: stage 8 x frames (fused relu + bf16 + transpose) ----
    if (t < 128) {    // zero halo cols 0,65 of all 8 frames
        const int r = t >> 4, chp = (t >> 3) & 1, sg = t & 7;
        *(bf16x8*)(&sA[(r * 66 + chp * 65) * SAS + sg * 8]) = (bf16x8)0;
    }
#pragma unroll 1
    for (int u = w; u < 64; u += 12) {       // (row r = u>>3, ic-group icg = u&7)
        const int r = u >> 3, icg = u & 7;
        if (icg < SGm) {                      // wave-uniform ic cull
            const int gy = y0 + r - 2;
            const float* __restrict__ src = x + (((size_t)n * 64 + icg * 8) * 64 + gy) * 64 + l;
            bf16x8 pk = (bf16x8)0;
            if ((unsigned)gy < 64u) {
#pragma unroll
                for (int j = 0; j < 8; ++j)
                    pk[j] = f2bf(fmaxf(src[j * HW], 0.f));
            }
            *(bf16x8*)(&sA[(r * 66 + l + 1) * SAS + icg * 8]) = pk;
        }
    }
    __syncthreads();   // B1: frames ready

    // ---- P1: half-row conv jobs ----
    f32x4 a0[2][4], a1[2][4];
#pragma unroll
    for (int i = 0; i < 2; ++i)
#pragma unroll
        for (int j = 0; j < 4; ++j) { a0[i][j] = 0.f; a1[i][j] = 0.f; }

    const int h = (w < 8) ? (w & 1) : ((w - 8) & 1);
    if (w < 8) {
        const int r = w >> 1;                         // out row / e1 row / e0 row
        conv3_dual_sw_half(sA, r + 1, WBe0, WBe1, c1, c2, h, lm, q, a0, a1);
    } else {
        const int f0 = (w < 10) ? 0 : 5;              // e0 rows -1 (frames 0-2), 4 (frames 5-7)
        conv3_sw_half(sA, f0, WBe0, c1, c2, h, lm, q, a0);
    }
    __syncthreads();   // B2: all x reads done -> frames may be overwritten

    // ---- n1 epi: e0 half-accs -> frames (zeros for OOB rows) ----
    if (w < 8) {
        const int r = w >> 1;
        epi_sw_half(&sA[(r + 1) * FR], 1, bias, nullptr, true, h, lm, q, a0);
    } else {
        const int row = (w < 10) ? -1 : 4;
        const int f0 = (w < 10) ? 0 : 5;
        epi_sw_half(&sA[f0 * FR], 1, bias, nullptr, (unsigned)(y0 + row) < 64u, h, lm, q, a0);
    }
    __syncthreads();   // B3: n1 ready -- LAST barrier

    // ---- P2: per-wave local stream (waves 0-7 only) ----
    if (w < 8) {
        const int r = w >> 1;
        // conv1_e0(n1 row r) accumulates into the live e1 half-acc
        conv1_sw_half(&sA[(r + 1) * FR], W1e0, c1, c2, h, lm, q, a1);
        // n2-half = relu(a1 + b1 + b2) -> own px half of slot r (wave-local)
        short* __restrict__ n2s = &sA[L_N2 + r * N2R];
        epi_sw_half(n2s, 0, bias + 64, bias + 128, true, h, lm, q, a1);
        // final half-acc: conv1_e1(n2) + e2 conv3(n1), both normal layout
#pragma unroll
        for (int i = 0; i < 2; ++i)
#pragma unroll
            for (int j = 0; j < 4; ++j) a0[i][j] = 0.f;
        conv1_nm_half(n2s, W1e1, c1, c2, h, lm, q, a0);
        conv3_nm_half(sA, r, WBe2, c1, c2, h, lm, q, a0);
        // combine + coalesced f32x4 store
        const int y = y0 + r;
#pragma unroll
        for (int nt = 0; nt < 4; ++nt) {
            const int oc = nt * 16 + lm;
            const float bvs = bias[192 + oc] + bias[256 + oc];
#pragma unroll
            for (int m = 0; m < 2; ++m) {
                const size_t ob = (((size_t)n * 64 + oc) * 64 + y) * 64 + (2 * h + m) * 16 + q * 4;
                const f32x4 s = *(const f32x4*)(x + ob);   // skip = raw x
                f32x4 v;
#pragma unroll
                for (int r2 = 0; r2 < 4; ++r2)
                    v[r2] = a0[m][nt][r2] + bvs + s[r2];
                *(f32x4*)(outp + ob) = v;   // oc>=c2: acc=bias=0 -> skip only
            }
        }
    }
}

// ---------------------------------------------------------------------------
extern "C" void kernel_launch(void* const* d_in, const int* in_sizes, int n_in,
                              void* d_out, int out_size, void* d_ws, size_t ws_size,
                              hipStream_t stream) {
    (void)in_sizes; (void)n_in; (void)out_size; (void)ws_size;
    const float* x  = (const float*)d_in[0];
    const float* a1 = (const float*)d_in[1];
    const float* a2 = (const float*)d_in[2];
    const float* w3 = (const float*)d_in[3];
    const float* w1 = (const float*)d_in[4];
    const float* bn = (const float*)d_in[5];
    char* ws = (char*)d_ws;

    static int attr_done = 0;
    if (!attr_done) {
        hipFuncSetAttribute((const void*)fused_cell_kernel,
                            hipFuncAttributeMaxDynamicSharedMemorySize,
                            LDS_SHORTS * 2);
        attr_done = 1;
    }

    prep_kernel<<<466, 256, 0, stream>>>(w3, w1, bn, a1, a2, ws);
    const dim3 gc(16, 32);   // y-tiles of 4 rows, n
    fused_cell_kernel<<<gc, 768, LDS_SHORTS * 2, stream>>>(x, ws, (float*)d_out);
}

// Round 7
// 124.382 us; speedup vs baseline: 1.0848x; 1.0848x over previous
//
#include <hip/hip_runtime.h>
#include <hip/hip_bf16.h>

#define DI __device__ __forceinline__
#define MFMA __builtin_amdgcn_mfma_f32_16x16x32_bf16

typedef __attribute__((ext_vector_type(8))) short bf16x8;   // 8 bf16 = 4 VGPRs (MFMA A/B frag)
typedef __attribute__((ext_vector_type(4))) short s16x4;    // 4 bf16 = 8 B (ds_write_b64)
typedef __attribute__((ext_vector_type(4))) float f32x4;    // MFMA C/D frag

constexpr int HW = 4096;
constexpr int SAS = 72;            // ic-stride in shorts (36 dwords -> 2-way banks, free)

// ---- workspace layout (bytes): weights only (~240 KB) ----
constexpr size_t OFF_WB3  = 0;                       // bf16 [3][9][64oc][64ic]
constexpr size_t OFF_WB1  = OFF_WB3 + 221184;        // bf16 [2][64oc][64ic]
constexpr size_t OFF_BIAS = OFF_WB1 + 16384;         // f32 [5][64]
constexpr size_t OFF_CC   = OFF_BIAS + 1280;         // int[2]

// ---- LDS layout (short offsets), dynamic 149,760 B ----
constexpr int FR    = 66 * SAS;          // 4752 shorts per frame/slot row
constexpr int L_N2  = 8 * FR;            // n2 scratch: 4 rows x 64 x SAS
constexpr int N2R   = 64 * SAS;          // 4608 shorts per n2/p3 row
constexpr int L_P3  = L_N2 + 4 * N2R;    // p3 exchange: 4 rows x 64oc x SAS
constexpr int L_TOT = L_P3 + 4 * N2R;    // 74880 shorts = 149760 B

DI int argmax8(const float* __restrict__ a) {
    int best = 0; float bv = a[0];
#pragma unroll
    for (int i = 1; i < 8; ++i) { float v = a[i]; if (v > bv) { bv = v; best = i; } }
    return best;
}

DI short f2bf(float v) {
    __hip_bfloat16 h = __float2bfloat16(v);
    return __builtin_bit_cast(short, h);
}

DI float bf2f(short s) {
    return __bfloat162float(__builtin_bit_cast(__hip_bfloat16, s));
}

// ---------------------------------------------------------------------------
// prep: c1,c2; weights -> bf16 frag order with BN scale + channel masks
// folded; per-edge bias (out-masked). Tiny kernel (~3 us).
// ---------------------------------------------------------------------------
__global__ __launch_bounds__(256) void prep_kernel(
    const float* __restrict__ w3, const float* __restrict__ w1,
    const float* __restrict__ bn, const float* __restrict__ a1,
    const float* __restrict__ a2, char* __restrict__ ws) {
    short* __restrict__ wb3  = (short*)(ws + OFF_WB3);
    short* __restrict__ wb1  = (short*)(ws + OFF_WB1);
    float* __restrict__ bias = (float*)(ws + OFF_BIAS);
    int*   __restrict__ cc   = (int*)(ws + OFF_CC);
    const int c1 = 8 * (argmax8(a1) + 1);
    const int c2 = 8 * (argmax8(a2) + 1);

    const int idx = blockIdx.x * 256 + threadIdx.x;
    if (idx < 110592) {                       // wb3 flat = ((e*9+kp)*64+oc)*64+ic
        const int e = idx / 36864, rem = idx % 36864;
        const int kp = rem >> 12, oc = (rem >> 6) & 63, ic = rem & 63;
        const int bnrow = (e == 0) ? 0 : (e == 1) ? 1 : 3;
        const float g = bn[(bnrow * 4 + 0) * 64 + oc];
        const float v = bn[(bnrow * 4 + 3) * 64 + oc];
        const float s = g * rsqrtf(v + 1e-5f);
        const float wv = w3[((e * 64 + oc) * 64 + ic) * 9 + kp];
        wb3[idx] = (oc < c2 && ic < c1) ? f2bf(wv * s) : (short)0;
    } else if (idx < 118784) {                // wb1 flat = (e*64+oc)*64+ic
        const int j = idx - 110592;
        const int e = j >> 12, oc = (j >> 6) & 63, ic = j & 63;
        const int bnrow = (e == 0) ? 2 : 4;
        const float g = bn[(bnrow * 4 + 0) * 64 + oc];
        const float v = bn[(bnrow * 4 + 3) * 64 + oc];
        const float s = g * rsqrtf(v + 1e-5f);
        wb1[j] = (oc < c2 && ic < c1) ? f2bf(w1[(e * 64 + oc) * 64 + ic] * s) : (short)0;
    } else if (idx < 119104) {                // bias
        const int j = idx - 118784;
        const int e = j >> 6, oc = j & 63;
        const float g = bn[(e * 4 + 0) * 64 + oc];
        const float b = bn[(e * 4 + 1) * 64 + oc];
        const float m = bn[(e * 4 + 2) * 64 + oc];
        const float v = bn[(e * 4 + 3) * 64 + oc];
        bias[j] = (oc < c2) ? (b - m * g * rsqrtf(v + 1e-5f)) : 0.f;
    } else if (idx == 119104) {
        cc[0] = c1; cc[1] = c2;
    }
}

// ---------------------------------------------------------------------------
// conv helpers. FULLY UNROLLED K-loops so the list scheduler pipelines the
// global weight loads (~200-400cy L2) and ds_reads (~120cy) across steps.
// s_setprio(1) around the MFMA clusters (T5: role-diverse waves exist at
// every phase -> scheduler can prefer the MFMA-issuing wave).
// All register indices compile-time.
// ---------------------------------------------------------------------------
// 3x3 conv, one row, SWAPPED operands (lane: px=mt*16+lm, oc=nt*16+q*4+r)
DI void conv3_sw1(const short* __restrict__ sA, int f0,
                  const short* __restrict__ WB, int c1, int c2,
                  int lm, int q, f32x4 (&acc)[4][4]) {
#pragma unroll
    for (int ky = 0; ky < 3; ++ky)
#pragma unroll
        for (int kx = 0; kx < 3; ++kx) {
            const short* __restrict__ W = WB + (ky * 3 + kx) * 4096;
#pragma unroll
            for (int kc = 0; kc < 2; ++kc)
                if (kc == 0 || c1 > 32) {
                    bf16x8 af[4], bfr[4];
#pragma unroll
                    for (int nt = 0; nt < 4; ++nt)
                        if (nt * 16 < c2)
                            bfr[nt] = *(const bf16x8*)(W + (nt * 16 + lm) * 64 + kc * 32 + q * 8);
#pragma unroll
                    for (int mt = 0; mt < 4; ++mt)
                        af[mt] = *(const bf16x8*)(&sA[((f0 + ky) * 66 + mt * 16 + lm + kx) * SAS + kc * 32 + q * 8]);
                    __builtin_amdgcn_s_setprio(1);
#pragma unroll
                    for (int nt = 0; nt < 4; ++nt)
                        if (nt * 16 < c2)
#pragma unroll
                            for (int mt = 0; mt < 4; ++mt)
                                acc[mt][nt] = MFMA(bfr[nt], af[mt], acc[mt][nt], 0, 0, 0);
                    __builtin_amdgcn_s_setprio(0);
                }
        }
}

// 3x3 conv, TWO rows sharing weight frags, swapped (dual-acc waves w6/w7).
// NOW fully unrolled like sw1 (round-4 lesson: unroll = the latency fix);
// at (512,2) the unified budget is 256 regs/wave: 128 acc + frags fits.
DI void conv3_sw2(const short* __restrict__ sA, int f0a, int f0b,
                  const short* __restrict__ WB, int c1, int c2,
                  int lm, int q, f32x4 (&accA)[4][4], f32x4 (&accB)[4][4]) {
#pragma unroll
    for (int ky = 0; ky < 3; ++ky)
#pragma unroll
        for (int kx = 0; kx < 3; ++kx) {
            const short* __restrict__ W = WB + (ky * 3 + kx) * 4096;
#pragma unroll
            for (int kc = 0; kc < 2; ++kc)
                if (kc == 0 || c1 > 32) {
                    bf16x8 afA[4], afB[4], bfr[4];
#pragma unroll
                    for (int nt = 0; nt < 4; ++nt)
                        if (nt * 16 < c2)
                            bfr[nt] = *(const bf16x8*)(W + (nt * 16 + lm) * 64 + kc * 32 + q * 8);
#pragma unroll
                    for (int mt = 0; mt < 4; ++mt) {
                        afA[mt] = *(const bf16x8*)(&sA[((f0a + ky) * 66 + mt * 16 + lm + kx) * SAS + kc * 32 + q * 8]);
                        afB[mt] = *(const bf16x8*)(&sA[((f0b + ky) * 66 + mt * 16 + lm + kx) * SAS + kc * 32 + q * 8]);
                    }
                    __builtin_amdgcn_s_setprio(1);
#pragma unroll
                    for (int nt = 0; nt < 4; ++nt)
                        if (nt * 16 < c2)
#pragma unroll
                            for (int mt = 0; mt < 4; ++mt) {
                                accA[mt][nt] = MFMA(bfr[nt], afA[mt], accA[mt][nt], 0, 0, 0);
                                accB[mt][nt] = MFMA(bfr[nt], afB[mt], accB[mt][nt], 0, 0, 0);
                            }
                    __builtin_amdgcn_s_setprio(0);
                }
        }
}

// 3x3 conv, one row, NORMAL operands (lane: oc=nt*16+lm, px=mt*16+q*4+r)
DI void conv3_nm1(const short* __restrict__ sA, int f0,
                  const short* __restrict__ WB, int c1, int c2,
                  int lm, int q, f32x4 (&acc)[4][4]) {
#pragma unroll
    for (int ky = 0; ky < 3; ++ky)
#pragma unroll
        for (int kx = 0; kx < 3; ++kx) {
            const short* __restrict__ W = WB + (ky * 3 + kx) * 4096;
#pragma unroll
            for (int kc = 0; kc < 2; ++kc)
                if (kc == 0 || c1 > 32) {
                    bf16x8 af[4], bfr[4];
#pragma unroll
                    for (int nt = 0; nt < 4; ++nt)
                        if (nt * 16 < c2)
                            bfr[nt] = *(const bf16x8*)(W + (nt * 16 + lm) * 64 + kc * 32 + q * 8);
#pragma unroll
                    for (int mt = 0; mt < 4; ++mt)
                        af[mt] = *(const bf16x8*)(&sA[((f0 + ky) * 66 + mt * 16 + lm + kx) * SAS + kc * 32 + q * 8]);
                    __builtin_amdgcn_s_setprio(1);
#pragma unroll
                    for (int nt = 0; nt < 4; ++nt)
                        if (nt * 16 < c2)
#pragma unroll
                            for (int mt = 0; mt < 4; ++mt)
                                acc[mt][nt] = MFMA(af[mt], bfr[nt], acc[mt][nt], 0, 0, 0);
                    __builtin_amdgcn_s_setprio(0);
                }
        }
}

// 1x1 conv, swapped, accumulate (input = n1 slot row, col = px+1)
DI void conv1_sw(const short* __restrict__ sRow, const short* __restrict__ W1,
                 int c1, int c2, int lm, int q, f32x4 (&acc)[4][4]) {
#pragma unroll
    for (int kc = 0; kc < 2; ++kc)
        if (kc == 0 || c1 > 32) {
            bf16x8 af[4], bfr[4];
#pragma unroll
            for (int mt = 0; mt < 4; ++mt)
                af[mt] = *(const bf16x8*)(&sRow[(mt * 16 + lm + 1) * SAS + kc * 32 + q * 8]);
#pragma unroll
            for (int nt = 0; nt < 4; ++nt)
                if (nt * 16 < c2)
                    bfr[nt] = *(const bf16x8*)(W1 + (nt * 16 + lm) * 64 + kc * 32 + q * 8);
            __builtin_amdgcn_s_setprio(1);
#pragma unroll
            for (int nt = 0; nt < 4; ++nt)
                if (nt * 16 < c2)
#pragma unroll
                    for (int mt = 0; mt < 4; ++mt)
                        acc[mt][nt] = MFMA(bfr[nt], af[mt], acc[mt][nt], 0, 0, 0);
            __builtin_amdgcn_s_setprio(0);
        }
}

// 1x1 conv, normal, accumulate (input = [px][ic] row, no col halo)
DI void conv1_nm(const short* __restrict__ sRow, const short* __restrict__ W1,
                 int c1, int c2, int lm, int q, f32x4 (&acc)[4][4]) {
#pragma unroll
    for (int kc = 0; kc < 2; ++kc)
        if (kc == 0 || c1 > 32) {
            bf16x8 af[4], bfr[4];
#pragma unroll
            for (int mt = 0; mt < 4; ++mt)
                af[mt] = *(const bf16x8*)(&sRow[(mt * 16 + lm) * SAS + kc * 32 + q * 8]);
#pragma unroll
            for (int nt = 0; nt < 4; ++nt)
                if (nt * 16 < c2)
                    bfr[nt] = *(const bf16x8*)(W1 + (nt * 16 + lm) * 64 + kc * 32 + q * 8);
            __builtin_amdgcn_s_setprio(1);
#pragma unroll
            for (int nt = 0; nt < 4; ++nt)
                if (nt * 16 < c2)
#pragma unroll
                    for (int mt = 0; mt < 4; ++mt)
                        acc[mt][nt] = MFMA(af[mt], bfr[nt], acc[mt][nt], 0, 0, 0);
            __builtin_amdgcn_s_setprio(0);
        }
}

// relu+bias epi from a SWAPPED acc into a [px][stride SAS] row.
DI void epi_sw(short* __restrict__ dst, int colOff, const float* __restrict__ b0,
               const float* __restrict__ b1, bool live, int lm, int q,
               const f32x4 (&acc)[4][4]) {
#pragma unroll
    for (int nt = 0; nt < 4; ++nt) {
        f32x4 bv = *(const f32x4*)(b0 + nt * 16 + q * 4);
        if (b1) {
            const f32x4 bvb = *(const f32x4*)(b1 + nt * 16 + q * 4);
#pragma unroll
            for (int r = 0; r < 4; ++r) bv[r] += bvb[r];
        }
#pragma unroll
        for (int mt = 0; mt < 4; ++mt) {
            s16x4 pk = (s16x4)0;
            if (live) {
#pragma unroll
                for (int r = 0; r < 4; ++r)
                    pk[r] = f2bf(fmaxf(acc[mt][nt][r] + bv[r], 0.f));
            }
            *(s16x4*)(&dst[(mt * 16 + lm + colOff) * SAS + nt * 16 + q * 4]) = pk;
        }
    }
}

// ---------------------------------------------------------------------------
// Fused cell kernel (round-4 verified structure: 512 thr / 8 waves / 4 out
// rows, 149.7 KB dynamic LDS, 4 barriers, no global n1/n2/p3). This round:
// conv3_sw2 fully unrolled + setprio around MFMA clusters + staging unroll 4.
// Roles: P1: w0-5 e0 rows 0-5, w6/w7 e1 row-pairs (dual acc). P2: w0-3 e2,
// w6/w7 conv1_e0 -> n2 -> conv1_e1 -> p3. P3: w0-3 combine + store.
// ---------------------------------------------------------------------------
__global__ __launch_bounds__(512, 2) void fused_cell_kernel(
    const float* __restrict__ x, const char* __restrict__ ws,
    float* __restrict__ outp) {
    extern __shared__ __align__(16) short sA[];
    const int t = threadIdx.x, w = t >> 6, l = t & 63, lm = l & 15, q = l >> 4;
    const int y0 = blockIdx.x * 4, n = blockIdx.y;
    const int* cc = (const int*)(ws + OFF_CC);
    const int c1 = __builtin_amdgcn_readfirstlane(cc[0]);
    const int c2 = __builtin_amdgcn_readfirstlane(cc[1]);
    const int SGm = (c1 > 32) ? 8 : 4;
    const float* __restrict__ bias = (const float*)(ws + OFF_BIAS);
    const short* __restrict__ WBe0 = (const short*)(ws + OFF_WB3);
    const short* __restrict__ WBe1 = WBe0 + 36864;
    const short* __restrict__ WBe2 = WBe0 + 2 * 36864;
    const short* __restrict__ W1e0 = (const short*)(ws + OFF_WB1);
    const short* __restrict__ W1e1 = W1e0 + 4096;

    f32x4 accA[4][4], accB[4][4];
#pragma unroll
    for (int i = 0; i < 4; ++i)
#pragma unroll
        for (int j = 0; j < 4; ++j) { accA[i][j] = 0.f; accB[i][j] = 0.f; }

    // ---- P0: stage 8 x frames (fused relu + bf16 + transpose) ----
    if (t < 128) {    // zero halo cols 0,65 of all 8 frames
        const int r = t >> 4, chp = (t >> 3) & 1, sg = t & 7;
        *(bf16x8*)(&sA[(r * 66 + chp * 65) * SAS + sg * 8]) = (bf16x8)0;
    }
    if (w < SGm) {    // wave w stages ic-group w for all 8 rows
#pragma unroll 4
        for (int r = 0; r < 8; ++r) {
            const int gy = y0 + r - 2;
            const float* __restrict__ src = x + (((size_t)n * 64 + w * 8) * 64 + gy) * 64 + l;
            bf16x8 pk = (bf16x8)0;
            if ((unsigned)gy < 64u) {
#pragma unroll
                for (int j = 0; j < 8; ++j)
                    pk[j] = f2bf(fmaxf(src[j * HW], 0.f));
            }
            *(bf16x8*)(&sA[(r * 66 + l + 1) * SAS + w * 8]) = pk;
        }
    }
    __syncthreads();   // B1: frames ready

    // ---- P1: all x-convs ----
    if (w < 6) {
        conv3_sw1(sA, w, WBe0, c1, c2, lm, q, accA);            // n1 row w
    } else if (w == 6) {
        conv3_sw2(sA, 1, 2, WBe1, c1, c2, lm, q, accA, accB);   // e1 out rows 0,1
    } else {
        conv3_sw2(sA, 3, 4, WBe1, c1, c2, lm, q, accA, accB);   // e1 out rows 2,3
    }
    __syncthreads();   // B2: x reads done -> frames become n1 slots

    // ---- n1 epi: rows 0-5 -> slots 0-5 (zero rows outside the image) ----
    if (w < 6) {
        const int gy = y0 - 1 + w;
        epi_sw(&sA[w * FR], 1, bias, nullptr, (unsigned)gy < 64u, lm, q, accA);
    }
    __syncthreads();   // B3: n1 ready

    // ---- P2: e2 (w0-3) and the n2/p3 chain (w6,w7) ----
    if (w < 4) {
        conv3_nm1(sA, w, WBe2, c1, c2, lm, q, accB);            // e2 out row w
    } else if (w >= 6) {
        const int ra = 2 * (w - 6), rb = ra + 1;
        // conv1_e0(n1 same y) accumulates into the e1 accs
        conv1_sw(&sA[(ra + 1) * FR], W1e0, c1, c2, lm, q, accA);
        conv1_sw(&sA[(rb + 1) * FR], W1e0, c1, c2, lm, q, accB);
        // n2 epi -> scratch rows (disjoint region, wave-private)
        epi_sw(&sA[L_N2 + ra * N2R], 0, bias + 64, bias + 128, true, lm, q, accA);
        epi_sw(&sA[L_N2 + rb * N2R], 0, bias + 64, bias + 128, true, lm, q, accB);
        // conv1_e1 (normal order) from scratch; reuse accs
#pragma unroll
        for (int i = 0; i < 4; ++i)
#pragma unroll
            for (int j = 0; j < 4; ++j) { accA[i][j] = 0.f; accB[i][j] = 0.f; }
        conv1_nm(&sA[L_N2 + ra * N2R], W1e1, c1, c2, lm, q, accA);
        conv1_nm(&sA[L_N2 + rb * N2R], W1e1, c1, c2, lm, q, accB);
        // p3 epi (bf16, normal layout [oc][px]) -> exchange region
#pragma unroll
        for (int nt = 0; nt < 4; ++nt) {
            const float bva = bias[256 + nt * 16 + lm];
#pragma unroll
            for (int mt = 0; mt < 4; ++mt) {
                s16x4 pa, pb;
#pragma unroll
                for (int r = 0; r < 4; ++r) {
                    pa[r] = f2bf(accA[mt][nt][r] + bva);
                    pb[r] = f2bf(accB[mt][nt][r] + bva);
                }
                *(s16x4*)(&sA[L_P3 + ra * N2R + (nt * 16 + lm) * SAS + mt * 16 + q * 4]) = pa;
                *(s16x4*)(&sA[L_P3 + rb * N2R + (nt * 16 + lm) * SAS + mt * 16 + q * 4]) = pb;
            }
        }
    }
    __syncthreads();   // B4: e2 + p3 ready

    // ---- P3: combine + coalesced f32x4 store (w0-3 own out rows 0-3) ----
    if (w < 4) {
        const int y = y0 + w;
        const float* __restrict__ bias3 = bias + 192;
#pragma unroll
        for (int nt = 0; nt < 4; ++nt) {
            const int oc = nt * 16 + lm;
            const float bvs = bias3[oc];
#pragma unroll
            for (int mt = 0; mt < 4; ++mt) {
                const s16x4 p = *(const s16x4*)(&sA[L_P3 + w * N2R + oc * SAS + mt * 16 + q * 4]);
                const size_t ob = (((size_t)n * 64 + oc) * 64 + y) * 64 + mt * 16 + q * 4;
                const f32x4 s = *(const f32x4*)(x + ob);   // skip = raw x
                f32x4 v;
#pragma unroll
                for (int r = 0; r < 4; ++r)
                    v[r] = accB[mt][nt][r] + bvs + bf2f(p[r]) + s[r];
                *(f32x4*)(outp + ob) = v;   // oc>=c2: acc=bias=p3=0 -> skip only
            }
        }
    }
}

// ---------------------------------------------------------------------------
extern "C" void kernel_launch(void* const* d_in, const int* in_sizes, int n_in,
                              void* d_out, int out_size, void* d_ws, size_t ws_size,
                              hipStream_t stream) {
    (void)in_sizes; (void)n_in; (void)out_size; (void)ws_size;
    const float* x  = (const float*)d_in[0];
    const float* a1 = (const float*)d_in[1];
    const float* a2 = (const float*)d_in[2];
    const float* w3 = (const float*)d_in[3];
    const float* w1 = (const float*)d_in[4];
    const float* bn = (const float*)d_in[5];
    char* ws = (char*)d_ws;

    static int attr_done = 0;
    if (!attr_done) {
        hipFuncSetAttribute((const void*)fused_cell_kernel,
                            hipFuncAttributeMaxDynamicSharedMemorySize,
                            L_TOT * 2);
        attr_done = 1;
    }

    prep_kernel<<<466, 256, 0, stream>>>(w3, w1, bn, a1, a2, ws);
    const dim3 gc(16, 32);   // y-tiles, n
    fused_cell_kernel<<<gc, 512, L_TOT * 2, stream>>>(x, ws, (float*)d_out);
}